// Round 7
// baseline (195.349 us; speedup 1.0000x reference)
//
#include <hip/hip_runtime.h>
#include <cstdint>
#include <cstddef>

// ---------------------------------------------------------------------------
// Style2ResidualBlock1DSrc: modulated conv1d (StyleGAN2-style) on MI355X.
// bf16 MFMA GEMM pipeline. R6 = R3 structure (best measured: 51.5us gemm)
// with 32x32x16 MFMA (m119: 2495 TF vs 2075 for 16x16 — ~20% more FLOP/cyc,
// half the MFMA issue count, same LDS frag-read bytes). R4 (occupancy) and
// R5 (explicit dbuf pipeline) both regressed — per-iter time is the SUM of
// LDS-pipe + matrix-pipe (barrier convoy, matches guide m131-m141 plateau).
// ---------------------------------------------------------------------------

#define LIN_SCALE  0.0625f           // 1/sqrt(256)
#define CONV_SCALE 0.014731391f      // 1/sqrt(512*9)

#define B_   16
#define CIN  512
#define COUT 512
#define T_   2048
#define TP   2050                    // T + 2 pad rows

typedef __bf16 bf16x8 __attribute__((ext_vector_type(8)));
typedef float  f32x16 __attribute__((ext_vector_type(16)));
typedef unsigned short u16x8 __attribute__((ext_vector_type(8)));
typedef unsigned short u16x2 __attribute__((ext_vector_type(2)));

#define AS1 __attribute__((address_space(1)))
#define AS3 __attribute__((address_space(3)))

__device__ inline unsigned short f2bf(float f) {
  __bf16 h = (__bf16)f;              // RNE fptrunc
  return __builtin_bit_cast(unsigned short, h);
}

// ---------------- 1. style linear: s[b][i] ----------------
__global__ __launch_bounds__(256) void style_kernel(const float* __restrict__ c_src,
                                                    const float* __restrict__ c_trg,
                                                    const float* __restrict__ sw,
                                                    const float* __restrict__ sb,
                                                    float* __restrict__ s) {
  __shared__ float c[256];
  const int b = blockIdx.y;
  const int tid = threadIdx.x;
  c[tid] = (tid < 128) ? c_src[b * 128 + tid] : c_trg[b * 128 + tid - 128];
  __syncthreads();
  const int w = tid >> 6, lane = tid & 63;
  #pragma unroll
  for (int rr = 0; rr < 16; ++rr) {
    const int i = blockIdx.x * 64 + w * 16 + rr;
    const float* row = sw + (size_t)i * 256;
    float acc = row[lane] * c[lane] + row[lane + 64] * c[lane + 64]
              + row[lane + 128] * c[lane + 128] + row[lane + 192] * c[lane + 192];
    #pragma unroll
    for (int off = 32; off; off >>= 1) acc += __shfl_down(acc, off, 64);
    if (lane == 0) s[b * 512 + i] = acc * LIN_SCALE + sb[i];
  }
}

// ---------------- 2. modulate + demodulate -> bf16 W[b][tap][o][i] ----------------
__global__ __launch_bounds__(256) void modw_kernel(const float* __restrict__ weight,
                                                   const float* __restrict__ s,
                                                   unsigned short* __restrict__ Wm) {
  const int o = blockIdx.x;
  const int tid = threadIdx.x;
  __shared__ float wsh[1536];        // weight[o][:][:]
  __shared__ float svs[16 * 512];    // all style vectors (32 KB)
  __shared__ float partial[16][4];
  __shared__ float demv[16];

  #pragma unroll
  for (int j = tid; j < 1536; j += 256) wsh[j] = weight[(size_t)o * 1536 + j];
  #pragma unroll
  for (int j = tid; j < 16 * 512; j += 256) svs[j] = s[j];
  __syncthreads();

  float wr[6];
  #pragma unroll
  for (int q = 0; q < 6; ++q) wr[q] = wsh[tid * 6 + q] * CONV_SCALE;

  const int lane = tid & 63, w = tid >> 6;
  float ssb[16];
  #pragma unroll
  for (int b = 0; b < 16; ++b) {
    const float s0 = svs[b * 512 + 2 * tid];
    const float s1 = svs[b * 512 + 2 * tid + 1];
    float ss = 0.f;
    #pragma unroll
    for (int q = 0; q < 3; ++q) { float v = wr[q] * s0; ss += v * v; }
    #pragma unroll
    for (int q = 3; q < 6; ++q) { float v = wr[q] * s1; ss += v * v; }
    ssb[b] = ss;
  }
  #pragma unroll
  for (int b = 0; b < 16; ++b) {
    float ss = ssb[b];
    #pragma unroll
    for (int off = 32; off; off >>= 1) ss += __shfl_down(ss, off, 64);
    if (lane == 0) partial[b][w] = ss;
  }
  __syncthreads();
  if (tid < 16)
    demv[tid] = rsqrtf(partial[tid][0] + partial[tid][1] + partial[tid][2] + partial[tid][3] + 1e-8f);
  __syncthreads();

  #pragma unroll
  for (int b = 0; b < 16; ++b) {
    const float dem = demv[b];
    const float s0 = svs[b * 512 + 2 * tid] * dem;
    const float s1 = svs[b * 512 + 2 * tid + 1] * dem;
    #pragma unroll
    for (int k = 0; k < 3; ++k) {
      u16x2 v;
      v.x = f2bf(wr[k] * s0);
      v.y = f2bf(wr[3 + k] * s1);
      *(u16x2*)&Wm[(((size_t)b * 3 + k) * 512 + o) * 512 + 2 * tid] = v;
    }
  }
}

// ---------------- 3. transpose + pad + bf16 (+ fused zpad) ----------------
__global__ __launch_bounds__(256) void transpose_kernel(const float* __restrict__ x,
                                                        unsigned short* __restrict__ xT) {
  __shared__ float tile[64][65];
  const int b = blockIdx.z, i0 = blockIdx.y * 64, t0 = blockIdx.x * 64;
  const int tid = threadIdx.x;

  const int lr = tid >> 4;            // 0..15
  const int lc = (tid & 15) * 4;      // float4
  const float* xb = x + ((size_t)b * CIN + i0) * T_ + t0;
  #pragma unroll
  for (int p = 0; p < 4; ++p) {
    const int r = p * 16 + lr;
    const float4 v = *(const float4*)(xb + (size_t)r * T_ + lc);
    tile[r][lc + 0] = v.x; tile[r][lc + 1] = v.y;
    tile[r][lc + 2] = v.z; tile[r][lc + 3] = v.w;
  }
  // fused zero-pad of rows 0 and 2049 (no barrier dependency)
  if (blockIdx.x == 0 && tid < 8)
    *(u16x8*)&xT[(size_t)b * TP * CIN + i0 + tid * 8] = (u16x8){0,0,0,0,0,0,0,0};
  if (blockIdx.x == gridDim.x - 1 && tid < 8)
    *(u16x8*)&xT[((size_t)b * TP + TP - 1) * CIN + i0 + tid * 8] = (u16x8){0,0,0,0,0,0,0,0};
  __syncthreads();

  const int st = tid >> 3;            // 0..31
  const int si = (tid & 7) * 8;       // 16B
  unsigned short* xTb = xT + ((size_t)b * TP + 1 + t0) * CIN + i0;
  #pragma unroll
  for (int p = 0; p < 2; ++p) {
    const int t = p * 32 + st;
    u16x8 v;
    #pragma unroll
    for (int q = 0; q < 8; ++q) v[q] = f2bf(tile[si + q][t]);
    *(u16x8*)&xTb[(size_t)t * CIN + si] = v;
  }
}

// ---------------- 4. main GEMM, tap-fused, 32x32x16 MFMA ----------------
// out[b][o0..+128][t0..+256] = sum_{tap,i} Wm[b][tap][o][i] * xT[b][t0+lt+tap][i]
// LDS: lA[3][128][32], lB[258][32], chunk-swizzled c^((row>>1)&3). 41.1 KB.
// 4 waves in 2(M)x2(N), each 64x128 via 2x4 tiles of 32x32 (f32x16 accs).
#define BM 128
#define BN 256
#define BK 32

__global__ __launch_bounds__(256, 2) void gemm_kernel(const unsigned short* __restrict__ Wm,
                                                      const unsigned short* __restrict__ xT,
                                                      float* __restrict__ out) {
  __shared__ unsigned short lA[3 * 128 * 32];   // 24576 B
  __shared__ unsigned short lB[258 * 32];       // 16512 B

  // XCD b-grouping: 512 blocks; ids == xcd (mod 8); 2 batches per XCD.
  const int id  = blockIdx.x;
  const int xcd = id & 7;
  const int j   = id >> 3;                 // 0..63
  const int b   = xcd + 8 * (j >> 5);      // 0..15
  const int r   = j & 31;
  const int o0  = (r >> 3) * BM;           // 4 o-blocks
  const int t0  = (r & 7) * BN;            // 8 t-blocks

  const int tid  = threadIdx.x;
  const int lane = tid & 63;
  const int wm   = ((tid >> 6) & 1) * 64;  // wave M offset
  const int wn   = (tid >> 7) * 128;       // wave N offset
  const int l31  = lane & 31;
  const int l5   = lane >> 5;              // k-group within frag

  const unsigned short* gW = Wm + ((size_t)b * 3 * 512 + o0) * 512;
  const unsigned short* gX = xT + ((size_t)b * TP + t0) * CIN;

  f32x16 acc[2][4];
  #pragma unroll
  for (int i = 0; i < 2; ++i)
    #pragma unroll
    for (int jj = 0; jj < 4; ++jj)
      #pragma unroll
      for (int e = 0; e < 16; ++e) acc[i][jj][e] = 0.f;

  for (int kk = 0; kk < 16; ++kk) {
    const int i0 = kk * 32;
    __syncthreads();                       // previous compute done
    // A: 1536 chunks (3 taps x 128 rows x 4), 6 per thread
    #pragma unroll
    for (int q = 0; q < 6; ++q) {
      const int ci  = q * 256 + tid;
      const int row = ci >> 2;             // tap*128 + ar
      const int tap = row >> 7;
      const int ar  = row & 127;
      const int gc  = ((ci & 3) ^ ((ar >> 1) & 3)) * 8;
      __builtin_amdgcn_global_load_lds(
          (const AS1 void*)(gW + (size_t)tap * 262144 + (size_t)ar * 512 + i0 + gc),
          (AS3 void*)(&lA[ci * 8]), 16, 0, 0);
    }
    // B: 258 rows x 4 chunks = 1032; 4 per thread + tail 8
    #pragma unroll
    for (int q = 0; q < 4; ++q) {
      const int ci  = q * 256 + tid;
      const int row = ci >> 2;
      const int gc  = ((ci & 3) ^ ((row >> 1) & 3)) * 8;
      __builtin_amdgcn_global_load_lds(
          (const AS1 void*)(gX + (size_t)row * CIN + i0 + gc),
          (AS3 void*)(&lB[ci * 8]), 16, 0, 0);
    }
    if (tid < 8) {
      const int ci  = 1024 + tid;
      const int row = ci >> 2;             // 256, 257
      const int gc  = ((ci & 3) ^ ((row >> 1) & 3)) * 8;
      __builtin_amdgcn_global_load_lds(
          (const AS1 void*)(gX + (size_t)row * CIN + i0 + gc),
          (AS3 void*)(&lB[ci * 8]), 16, 0, 0);
    }
    __syncthreads();                       // staging visible

    #pragma unroll
    for (int tap = 0; tap < 3; ++tap) {
      // A frag (32x32x16): m = lane&31, k = (lane>>5)*8 + j.
      // k-half h (0/1): logical chunk = 2h + l5, swizzled ^((row>>1)&3).
      bf16x8 af[2][2], bfr[4][2];
      #pragma unroll
      for (int mt = 0; mt < 2; ++mt) {
        const int ra = wm + mt * 32 + l31;
        const int sw = (ra >> 1) & 3;
        #pragma unroll
        for (int h = 0; h < 2; ++h)
          af[mt][h] = *(const bf16x8*)&lA[((tap * 128 + ra) * 4 + ((2 * h + l5) ^ sw)) * 8];
      }
      #pragma unroll
      for (int nt = 0; nt < 4; ++nt) {
        const int rb = wn + nt * 32 + l31 + tap;
        const int sw = (rb >> 1) & 3;
        #pragma unroll
        for (int h = 0; h < 2; ++h)
          bfr[nt][h] = *(const bf16x8*)&lB[(rb * 4 + ((2 * h + l5) ^ sw)) * 8];
      }
      #pragma unroll
      for (int h = 0; h < 2; ++h)
        #pragma unroll
        for (int mt = 0; mt < 2; ++mt)
          #pragma unroll
          for (int nt = 0; nt < 4; ++nt)
            acc[mt][nt] = __builtin_amdgcn_mfma_f32_32x32x16_bf16(af[mt][h], bfr[nt][h], acc[mt][nt], 0, 0, 0);
    }
  }

  // epilogue (32x32 C/D, m74/m101): col = lane&31,
  // row = (reg&3) + 8*(reg>>2) + 4*(lane>>5)
  float* ob = out + ((size_t)b * COUT + o0 + wm) * T_ + t0 + wn;
  #pragma unroll
  for (int mt = 0; mt < 2; ++mt)
    #pragma unroll
    for (int nt = 0; nt < 4; ++nt)
      #pragma unroll
      for (int reg = 0; reg < 16; ++reg) {
        const int rrow = mt * 32 + (reg & 3) + 8 * (reg >> 2) + 4 * l5;
        ob[(size_t)rrow * T_ + nt * 32 + l31] = acc[mt][nt][reg];
      }
}

// ---------------------------------------------------------------------------
extern "C" void kernel_launch(void* const* d_in, const int* in_sizes, int n_in,
                              void* d_out, int out_size, void* d_ws, size_t ws_size,
                              hipStream_t stream) {
  const float* x       = (const float*)d_in[0];   // [16,512,2048]
  const float* c_src   = (const float*)d_in[1];   // [16,128]
  const float* c_trg   = (const float*)d_in[2];   // [16,128]
  const float* style_w = (const float*)d_in[3];   // [512,256]
  const float* style_b = (const float*)d_in[4];   // [512]
  const float* weight  = (const float*)d_in[5];   // [1,512,512,3]
  float* out = (float*)d_out;

  // workspace: s_buf fp32 [16][512] @0; Wm bf16 [16][3][512][512] @32768;
  //            xT bf16 [16][2050][512] @25198592
  char* ws = (char*)d_ws;
  float* s_buf          = (float*)ws;
  unsigned short* Wm    = (unsigned short*)(ws + 32768);
  unsigned short* xTbuf = (unsigned short*)(ws + 32768 + 25165824);

  style_kernel<<<dim3(8, 16), 256, 0, stream>>>(c_src, c_trg, style_w, style_b, s_buf);
  modw_kernel<<<dim3(COUT), 256, 0, stream>>>(weight, s_buf, Wm);
  transpose_kernel<<<dim3(T_ / 64, CIN / 64, B_), 256, 0, stream>>>(x, xTbuf);
  gemm_kernel<<<dim3(512), 256, 0, stream>>>(Wm, xTbuf, out);
}